// Round 1
// baseline (258.418 us; speedup 1.0000x reference)
//
#include <hip/hip_runtime.h>
#include <cstddef>

#define BATCH 8
#define NQ 16384
#define NK 16384
#define FEAT 128
#define MID 16
#define CTXD 128
#define OUTD 128
#define EPSV 1e-5f

#define ROWS 256

// ws layout (floats):
//   U     [BATCH][MID][CTXD]  : offset 0      (16384)
//   sumw  [BATCH][MID]        : offset 16384  (128)
//   st    [2][MID]            : offset 16512  (32)   (BN sum, sumsq per m)
//   lam   [BATCH][MID][OUTD]  : offset 16544  (16384)

// ---------------------------------------------------------------------------
// Phase 1: per (b, 256-row slab): key = ctx@Wk, w = exp(key) (no max-sub: |key|<~4),
// then U[b][m][d] += sum_n w[n][m]*ctx[n][d], sumw[b][m] += sum_n w[n][m].
// ---------------------------------------------------------------------------
__global__ __launch_bounds__(256) void k_phase1(
    const float* __restrict__ ctx, const float* __restrict__ Wk,
    float* __restrict__ U, float* __restrict__ sumw)
{
    const int b  = blockIdx.y;
    const int r0 = blockIdx.x * ROWS;
    const int t  = threadIdx.x;
    __shared__ float wL[ROWS][MID];   // 16 KiB

    // pass 1: thread-per-row key + exp
    {
        const int r = r0 + t;
        const float4* cp = (const float4*)(ctx + ((size_t)b * NK + r) * CTXD);
        float key[MID];
        #pragma unroll
        for (int m = 0; m < MID; ++m) key[m] = 0.f;
        #pragma unroll 4
        for (int kc = 0; kc < CTXD / 4; ++kc) {
            float4 c4 = cp[kc];
            float cf[4] = {c4.x, c4.y, c4.z, c4.w};
            #pragma unroll
            for (int j = 0; j < 4; ++j) {
                #pragma unroll
                for (int m = 0; m < MID; ++m)
                    key[m] += cf[j] * Wk[(4 * kc + j) * MID + m];  // uniform addr -> s_load
            }
        }
        #pragma unroll
        for (int m = 0; m < MID; ++m) wL[t][m] = __expf(key[m]);
    }
    __syncthreads();

    // pass 2: d-column threads accumulate U; ctx re-read coalesced (L2-hot)
    const int d = t & 127;
    const int h = t >> 7;
    float acc[MID];
    #pragma unroll
    for (int m = 0; m < MID; ++m) acc[m] = 0.f;
    for (int n = h; n < ROWS; n += 2) {
        float c = ctx[((size_t)b * NK + r0 + n) * CTXD + d];
        const float4* wp = (const float4*)wL[n];          // uniform addr broadcast
        float4 ww[4] = {wp[0], wp[1], wp[2], wp[3]};
        const float* wf = (const float*)ww;
        #pragma unroll
        for (int m = 0; m < MID; ++m) acc[m] += wf[m] * c;
    }
    // sumw partials (16 lanes; overlaps with others finishing pass 2)
    if (t < MID) {
        float s = 0.f;
        for (int n = 0; n < ROWS; ++n) s += wL[n][t];
        atomicAdd(&sumw[b * MID + t], s);
    }
    __syncthreads();
    if (h == 1) {
        #pragma unroll
        for (int m = 0; m < MID; ++m) wL[d][m] = acc[m];
    }
    __syncthreads();
    if (h == 0) {
        #pragma unroll
        for (int m = 0; m < MID; ++m)
            atomicAdd(&U[((size_t)b * MID + m) * CTXD + d], acc[m] + wL[d][m]);
    }
}

// ---------------------------------------------------------------------------
// Phase 2: lam[b][m][d] = (U[b][m] @ Wv[:,d]) / sumw[b][m]; BN stats via
// wave-reduced atomics. grid (8, BATCH), 256 thr.
// ---------------------------------------------------------------------------
__global__ __launch_bounds__(256) void k_lam(
    const float* __restrict__ U, const float* __restrict__ sumw,
    const float* __restrict__ Wv, float* __restrict__ lam, float* __restrict__ st)
{
    const int b = blockIdx.y;
    const int e = blockIdx.x * 256 + threadIdx.x;   // 0..2047
    const int m = e >> 7;
    const int d = e & 127;
    const float* u = U + ((size_t)b * MID + m) * CTXD;
    float dot = 0.f;
    #pragma unroll 8
    for (int k = 0; k < CTXD; ++k)
        dot += u[k] * Wv[k * OUTD + d];             // u[k] broadcast, Wv coalesced
    float l = dot / sumw[b * MID + m];
    lam[((size_t)b * MID + m) * OUTD + d] = l;
    float s1 = l, s2 = l * l;
    #pragma unroll
    for (int off = 32; off > 0; off >>= 1) {        // m is wave-uniform here
        s1 += __shfl_down(s1, off);
        s2 += __shfl_down(s2, off);
    }
    if ((threadIdx.x & 63) == 0) {
        atomicAdd(&st[m], s1);
        atomicAdd(&st[MID + m], s2);
    }
}

// ---------------------------------------------------------------------------
// Phase 3: bn from stats (recomputed per block, cheap), q = feat@Wq,
// out = q@bn. grid (NQ/ROWS, BATCH), 256 thr.
// ---------------------------------------------------------------------------
__global__ __launch_bounds__(256) void k_out(
    const float* __restrict__ feat, const float* __restrict__ Wq,
    const float* __restrict__ lam, const float* __restrict__ st,
    const float* __restrict__ gamma, const float* __restrict__ beta,
    float* __restrict__ out)
{
    const int b  = blockIdx.y;
    const int r0 = blockIdx.x * ROWS;
    const int t  = threadIdx.x;
    __shared__ float bnL[MID][OUTD];   // 8 KiB
    __shared__ float qL[ROWS][MID];    // 16 KiB

    for (int e = t; e < MID * OUTD; e += 256) {
        int m = e >> 7, d = e & 127;
        float mean = st[m] * (1.f / (BATCH * OUTD));
        float var  = st[MID + m] * (1.f / (BATCH * OUTD)) - mean * mean;
        float inv  = rsqrtf(var + EPSV);
        bnL[m][d] = (lam[((size_t)b * MID + m) * OUTD + d] - mean) * inv * gamma[m] + beta[m];
    }

    // query: thread-per-row
    {
        const int r = r0 + t;
        const float4* fp = (const float4*)(feat + ((size_t)b * NQ + r) * FEAT);
        float q[MID];
        #pragma unroll
        for (int m = 0; m < MID; ++m) q[m] = 0.f;
        #pragma unroll 4
        for (int kc = 0; kc < FEAT / 4; ++kc) {
            float4 f4 = fp[kc];
            float ff[4] = {f4.x, f4.y, f4.z, f4.w};
            #pragma unroll
            for (int j = 0; j < 4; ++j) {
                #pragma unroll
                for (int m = 0; m < MID; ++m)
                    q[m] += ff[j] * Wq[(4 * kc + j) * MID + m];
            }
        }
        #pragma unroll
        for (int m = 0; m < MID; ++m) qL[t][m] = q[m];
    }
    __syncthreads();

    // out: d-column threads, coalesced store
    const int d = t & 127;
    const int h = t >> 7;
    float bnr[MID];
    #pragma unroll
    for (int m = 0; m < MID; ++m) bnr[m] = bnL[m][d];
    for (int n = h; n < ROWS; n += 2) {
        const float4* qp = (const float4*)qL[n];
        float4 qq[4] = {qp[0], qp[1], qp[2], qp[3]};
        const float* qf = (const float*)qq;
        float o = 0.f;
        #pragma unroll
        for (int m = 0; m < MID; ++m) o += qf[m] * bnr[m];
        out[((size_t)b * NQ + r0 + n) * OUTD + d] = o;
    }
}

extern "C" void kernel_launch(void* const* d_in, const int* in_sizes, int n_in,
                              void* d_out, int out_size, void* d_ws, size_t ws_size,
                              hipStream_t stream)
{
    const float* feat  = (const float*)d_in[0];
    const float* ctx   = (const float*)d_in[1];
    const float* Wq    = (const float*)d_in[2];
    const float* Wk    = (const float*)d_in[3];
    const float* Wv    = (const float*)d_in[4];
    const float* gamma = (const float*)d_in[5];
    const float* beta  = (const float*)d_in[6];
    float* out = (float*)d_out;

    float* ws   = (float*)d_ws;
    float* U    = ws;            // 16384
    float* sumw = ws + 16384;    // 128
    float* st   = ws + 16512;    // 32
    float* lam  = ws + 16544;    // 16384

    hipMemsetAsync(d_ws, 0, 16544 * sizeof(float), stream);
    k_phase1<<<dim3(NK / ROWS, BATCH), 256, 0, stream>>>(ctx, Wk, U, sumw);
    k_lam<<<dim3(8, BATCH), 256, 0, stream>>>(U, sumw, Wv, lam, st);
    k_out<<<dim3(NQ / ROWS, BATCH), 256, 0, stream>>>(feat, Wq, lam, st, gamma, beta, out);
}